// Round 10
// baseline (59.235 us; speedup 1.0000x reference)
//
#include <hip/hip_runtime.h>

// Chamfer distance, B=4, N=8192, fp32 3-D points, MI355X.
// Round 10: MEASUREMENT ROUND. r9 structure, with:
//  - duplicate-work grid (copy bit, 2048 blocks): main runs 2x so its dur
//    (~60us) exceeds the harness poison-fills (~40us) and its counter row
//    (VGPR_Count / FETCH_SIZE / VALUBusy / MfmaUtil / Occupancy) becomes
//    visible in top-5. Real main cost = visible dur / 2. Copy 1 writes a
//    duplicate ws_row region that reduce ignores (deterministic).
//  - anti-spill: __launch_bounds__(256,2) -> 256-reg budget (LDS already
//    caps residency at 2 blocks/CU, so no occupancy loss) and unroll 2
//    (halves fresh "=&v" acc tuples per scheduling region).
// K-slot packing (verified r3-r9):
//   A g0={hx,hy,hz,hx,hy,hz,lx,ly}  g1={lz,sh,sl,1,1,0,0,0}
//   B g0={-2hx,-2hy,-2hz,-2lx,-2ly,-2lz,-2hx,-2hy}  g1={-2hz,1,1,sh,sl,0,0,0}

typedef _Float16 half8  __attribute__((ext_vector_type(8)));
typedef float    f32x16 __attribute__((ext_vector_type(16)));

#define NPTS   8192
#define NB     4
#define SPLITS 4
#define TPW    64                  // B-tiles per window
#define QWIN   (TPW * 32)          // 2048 q-points per window

#define MFMA_V(d, a, b, c)                                             \
    asm("v_mfma_f32_32x32x16_f16 %0, %1, %2, %3"                       \
        : "=&v"(d) : "v"(a), "v"(b), "v"(c))

// ---------- main: 2048 blocks x 256 thr (4 waves) ----------
// block = (copy, dir, b, qsplit, ptile-of-256); wave = 64 p-rows (2 A-tiles).
__global__ __launch_bounds__(256, 2) void chamfer_main(
    const float* __restrict__ pc1, const float* __restrict__ pc2,
    float* __restrict__ ws_row)
{
    __shared__ half8 Bf[(TPW + 4) * 64];   // +4 pad tiles for prefetch tail

    int bid = blockIdx.x;
    const int pt   = bid & 31;            bid >>= 5;
    const int qs   = bid & (SPLITS - 1);  bid >>= 2;
    const int b    = bid & (NB - 1);      bid >>= 2;
    const int dir  = bid & 1;             bid >>= 1;
    const int copy = bid;                 // 0/1: identical work, distinct output

    const int tid = threadIdx.x;
    const int w = tid >> 6, lane = tid & 63;
    const int col = lane & 31, g = lane >> 5;
    const int pbase = pt * 256 + w * 64;

    const float* Acl = dir ? pc2 : pc1;        // row side
    const float* Bcl = dir ? pc1 : pc2;        // col side

    const _Float16 one = (_Float16)1.0f, zz = (_Float16)0.0f;

    // ---- build this block's B-fragment window in LDS ----
    for (int i = tid; i < QWIN; i += 256) {
        const int t = i >> 5, c = i & 31;
        const float* Q = Bcl + ((size_t)b * NPTS + qs * QWIN + i) * 3;
        const float qx = Q[0], qy = Q[1], qz = Q[2];

        const _Float16 hx = (_Float16)qx, hy = (_Float16)qy, hz = (_Float16)qz;
        const _Float16 lx = (_Float16)(qx - (float)hx);
        const _Float16 ly = (_Float16)(qy - (float)hy);
        const _Float16 lz = (_Float16)(qz - (float)hz);
        const float sq = fmaf(qx, qx, fmaf(qy, qy, qz * qz));
        const _Float16 sh = (_Float16)sq;
        const _Float16 sl = (_Float16)(sq - (float)sh);

        const _Float16 nhx = (_Float16)(-2.0f * (float)hx);
        const _Float16 nhy = (_Float16)(-2.0f * (float)hy);
        const _Float16 nhz = (_Float16)(-2.0f * (float)hz);
        const _Float16 nlx = (_Float16)(-2.0f * (float)lx);
        const _Float16 nly = (_Float16)(-2.0f * (float)ly);
        const _Float16 nlz = (_Float16)(-2.0f * (float)lz);

        Bf[t * 64 + c]      = (half8){nhx, nhy, nhz, nlx, nly, nlz, nhx, nhy};
        Bf[t * 64 + 32 + c] = (half8){nhz, one, one, sh,  sl,  zz,  zz,  zz};
    }

    // ---- A fragments ----
    half8 a0, a1;
    #pragma unroll
    for (int h = 0; h < 2; ++h) {
        const float* P = Acl + ((size_t)b * NPTS + pbase + h * 32 + col) * 3;
        const float px = P[0], py = P[1], pz = P[2];
        const _Float16 hx = (_Float16)px, hy = (_Float16)py, hz = (_Float16)pz;
        const _Float16 lx = (_Float16)(px - (float)hx);
        const _Float16 ly = (_Float16)(py - (float)hy);
        const _Float16 lz = (_Float16)(pz - (float)hz);
        const float sq1 = fmaf(px, px, fmaf(py, py, pz * pz));
        const _Float16 sh = (_Float16)sq1;
        const _Float16 sl = (_Float16)(sq1 - (float)sh);
        half8 a;
        if (g == 0) a = (half8){hx, hy, hz, hx, hy, hz, lx, ly};
        else        a = (half8){lz, sh, sl, one, one, zz, zz, zz};
        if (h == 0) a0 = a; else a1 = a;
    }

    f32x16 rowmin0, rowmin1;
    #pragma unroll
    for (int r = 0; r < 16; ++r) { rowmin0[r] = 3.402823466e+38f;
                                   rowmin1[r] = 3.402823466e+38f; }
    f32x16 zero16;
    #pragma unroll
    for (int r = 0; r < 16; ++r) zero16[r] = 0.0f;

    __syncthreads();   // LDS build complete; read-only from here on

    // ---- 4-tile register ring; no barriers in the loop ----
    half8 p0 = Bf[0 * 64 + lane], p1 = Bf[1 * 64 + lane];
    half8 p2 = Bf[2 * 64 + lane], p3 = Bf[3 * 64 + lane];

    #pragma unroll 2
    for (int t = 0; t < TPW; t += 2) {
        const half8 m0 = Bf[(t + 4) * 64 + lane];
        const half8 m1 = Bf[(t + 5) * 64 + lane];

        f32x16 acc00, acc01, acc10, acc11;
        MFMA_V(acc00, a0, p0, zero16);
        MFMA_V(acc01, a0, p1, zero16);
        MFMA_V(acc10, a1, p0, zero16);
        MFMA_V(acc11, a1, p1, zero16);

        __builtin_amdgcn_sched_barrier(0);
        asm volatile("s_nop 7\n\ts_nop 7");
        __builtin_amdgcn_sched_barrier(0);

        #pragma unroll
        for (int r = 0; r < 16; ++r)
            rowmin0[r] = fminf(fminf(acc00[r], acc01[r]), rowmin0[r]);
        #pragma unroll
        for (int r = 0; r < 16; ++r)
            rowmin1[r] = fminf(fminf(acc10[r], acc11[r]), rowmin1[r]);

        p0 = p2; p1 = p3; p2 = m0; p3 = m1;
    }

    // ---- cross-column min + store; row map (r&3)+8*(r>>2)+4*g ----
    const size_t obase =
        ((((size_t)copy * 2 + dir) * NB + b) * SPLITS + qs) * NPTS + pbase;
    #pragma unroll
    for (int r = 0; r < 16; ++r) {
        float v = rowmin0[r];
        v = fminf(v, __shfl_xor(v, 1, 64));
        v = fminf(v, __shfl_xor(v, 2, 64));
        v = fminf(v, __shfl_xor(v, 4, 64));
        v = fminf(v, __shfl_xor(v, 8, 64));
        v = fminf(v, __shfl_xor(v, 16, 64));
        float u = rowmin1[r];
        u = fminf(u, __shfl_xor(u, 1, 64));
        u = fminf(u, __shfl_xor(u, 2, 64));
        u = fminf(u, __shfl_xor(u, 4, 64));
        u = fminf(u, __shfl_xor(u, 8, 64));
        u = fminf(u, __shfl_xor(u, 16, 64));
        if (col == 0) {
            const int row = (r & 3) + 8 * (r >> 2) + 4 * g;
            ws_row[obase + row]      = v;
            ws_row[obase + 32 + row] = u;
        }
    }
}

// ---------- reduce: 256 blocks; copy-0 only; min over 4 splits ----------
__global__ __launch_bounds__(256) void chamfer_reduce(
    const float* __restrict__ ws_row, float* __restrict__ partial)
{
    int bid = blockIdx.x;                    // 2 dir x 4 b x 32 slices
    const int sl  = bid & 31; bid >>= 5;
    const int b   = bid & 3;  bid >>= 2;
    const int dir = bid;

    const int p = sl * 256 + threadIdx.x;
    const float* base =
        ws_row + (((size_t)dir * NB + b) * SPLITS) * NPTS + p;   // copy 0
    float sum = fminf(fminf(base[0],        base[NPTS]),
                      fminf(base[2 * NPTS], base[3 * NPTS]));

    for (int off = 32; off; off >>= 1) sum += __shfl_down(sum, off, 64);
    __shared__ float red[4];
    if (!(threadIdx.x & 63)) red[threadIdx.x >> 6] = sum;
    __syncthreads();
    if (!threadIdx.x)
        partial[blockIdx.x] = red[0] + red[1] + red[2] + red[3];
}

// ---------- final: 4 blocks x 64 thr ----------
__global__ __launch_bounds__(64) void chamfer_final(
    const float* __restrict__ partial, float* __restrict__ out)
{
    const int b = blockIdx.x, t = threadIdx.x;
    const int dir = t >> 5, sl = t & 31;
    float v = partial[(((size_t)dir * NB + b) << 5) + sl];
    for (int off = 32; off; off >>= 1) v += __shfl_down(v, off, 64);
    if (!t) out[b] = v * (1.0f / (float)NPTS);
}

extern "C" void kernel_launch(void* const* d_in, const int* in_sizes, int n_in,
                              void* d_out, int out_size, void* d_ws, size_t ws_size,
                              hipStream_t stream)
{
    const float* pc1 = (const float*)d_in[0];
    const float* pc2 = (const float*)d_in[1];
    float* out = (float*)d_out;

    char* ws = (char*)d_ws;
    float* ws_row  = (float*)ws;                // 2 copies * 1 MiB = 2 MiB
    float* partial = (float*)(ws + (2 << 20));  // 1 KiB

    chamfer_main<<<2048, 256, 0, stream>>>(pc1, pc2, ws_row);
    chamfer_reduce<<<256, 256, 0, stream>>>(ws_row, partial);
    chamfer_final<<<NB, 64, 0, stream>>>(partial, out);
}

// Round 11
// 35.058 us; speedup vs baseline: 1.6896x; 1.6896x over previous
//
#include <hip/hip_runtime.h>

// Chamfer distance, B=4, N=8192, fp32 3-D points, MI355X.
// Round 11: fix the two r10-measured killers (AGPR shuffling + low occupancy):
//  - phase-split inner loop: only 2 "=&v" f32x16 acc tuples live at a time
//  - rowmin = 32 SCALAR floats (no VReg_512 fragmentation) folded via pinned
//    v_min3_f32 inline asm -> allocator keeps them in arch VGPRs
//  - TPW=32 (LDS 34KB -> 4 blocks/CU), SPLITS=8, __launch_bounds__(256,4)
//    (128-reg cap -> 4 waves/SIMD, 16 waves/CU = 2x r10 occupancy)
// K-slot packing (verified r3-r10):
//   A g0={hx,hy,hz,hx,hy,hz,lx,ly}  g1={lz,sh,sl,1,1,0,0,0}
//   B g0={-2hx,-2hy,-2hz,-2lx,-2ly,-2lz,-2hx,-2hy}  g1={-2hz,1,1,sh,sl,0,0,0}
//   => acc = sq1 + sq2 - 2 p.q   (l.l' term ~2e-5 dropped, << 9.5e-4 thr)

typedef _Float16 half8  __attribute__((ext_vector_type(8)));
typedef float    f32x16 __attribute__((ext_vector_type(16)));

#define NPTS   8192
#define NB     4
#define SPLITS 8
#define TPW    32                  // B-tiles per window
#define QWIN   (TPW * 32)          // 1024 q-points per window

#define MFMA_V(d, a, b, c)                                             \
    asm("v_mfma_f32_32x32x16_f16 %0, %1, %2, %3"                       \
        : "=&v"(d) : "v"(a), "v"(b), "v"(c))

#define MIN3(dst, s0, s1)                                              \
    asm("v_min3_f32 %0, %1, %2, %0"                                    \
        : "+v"(dst) : "v"(s0), "v"(s1))

// ---------- main: 2048 blocks x 256 thr (4 waves) ----------
// block = (dir, b, qsplit-of-8, ptile-of-256); wave = 64 p-rows (2 A-tiles).
__global__ __launch_bounds__(256, 4) void chamfer_main(
    const float* __restrict__ pc1, const float* __restrict__ pc2,
    float* __restrict__ ws_row)
{
    __shared__ half8 Bf[(TPW + 2) * 64];   // +2 pad tiles for prefetch tail

    int bid = blockIdx.x;
    const int pt  = bid & 31;            bid >>= 5;
    const int qs  = bid & (SPLITS - 1);  bid >>= 3;
    const int b   = bid & (NB - 1);      bid >>= 2;
    const int dir = bid;

    const int tid = threadIdx.x;
    const int w = tid >> 6, lane = tid & 63;
    const int col = lane & 31, g = lane >> 5;
    const int pbase = pt * 256 + w * 64;

    const float* Acl = dir ? pc2 : pc1;        // row side
    const float* Bcl = dir ? pc1 : pc2;        // col side

    const _Float16 one = (_Float16)1.0f, zz = (_Float16)0.0f;

    // ---- build this block's B-fragment window in LDS (4 points/thread) ----
    for (int i = tid; i < QWIN; i += 256) {
        const int t = i >> 5, c = i & 31;
        const float* Q = Bcl + ((size_t)b * NPTS + qs * QWIN + i) * 3;
        const float qx = Q[0], qy = Q[1], qz = Q[2];

        const _Float16 hx = (_Float16)qx, hy = (_Float16)qy, hz = (_Float16)qz;
        const _Float16 lx = (_Float16)(qx - (float)hx);
        const _Float16 ly = (_Float16)(qy - (float)hy);
        const _Float16 lz = (_Float16)(qz - (float)hz);
        const float sq = fmaf(qx, qx, fmaf(qy, qy, qz * qz));
        const _Float16 sh = (_Float16)sq;
        const _Float16 sl = (_Float16)(sq - (float)sh);

        const _Float16 nhx = (_Float16)(-2.0f * (float)hx);
        const _Float16 nhy = (_Float16)(-2.0f * (float)hy);
        const _Float16 nhz = (_Float16)(-2.0f * (float)hz);
        const _Float16 nlx = (_Float16)(-2.0f * (float)lx);
        const _Float16 nly = (_Float16)(-2.0f * (float)ly);
        const _Float16 nlz = (_Float16)(-2.0f * (float)lz);

        Bf[t * 64 + c]      = (half8){nhx, nhy, nhz, nlx, nly, nlz, nhx, nhy};
        Bf[t * 64 + 32 + c] = (half8){nhz, one, one, sh,  sl,  zz,  zz,  zz};
    }

    // ---- A fragments (rows pbase+col, pbase+32+col) ----
    half8 a0, a1;
    #pragma unroll
    for (int h = 0; h < 2; ++h) {
        const float* P = Acl + ((size_t)b * NPTS + pbase + h * 32 + col) * 3;
        const float px = P[0], py = P[1], pz = P[2];
        const _Float16 hx = (_Float16)px, hy = (_Float16)py, hz = (_Float16)pz;
        const _Float16 lx = (_Float16)(px - (float)hx);
        const _Float16 ly = (_Float16)(py - (float)hy);
        const _Float16 lz = (_Float16)(pz - (float)hz);
        const float sq1 = fmaf(px, px, fmaf(py, py, pz * pz));
        const _Float16 sh = (_Float16)sq1;
        const _Float16 sl = (_Float16)(sq1 - (float)sh);
        half8 a;
        if (g == 0) a = (half8){hx, hy, hz, hx, hy, hz, lx, ly};
        else        a = (half8){lz, sh, sl, one, one, zz, zz, zz};
        if (h == 0) a0 = a; else a1 = a;
    }

    // rowmins as SCALARS (no 16-reg contiguity pressure)
    float rm0[16], rm1[16];
    #pragma unroll
    for (int r = 0; r < 16; ++r) { rm0[r] = 3.402823466e+38f;
                                   rm1[r] = 3.402823466e+38f; }
    f32x16 zero16;
    #pragma unroll
    for (int r = 0; r < 16; ++r) zero16[r] = 0.0f;

    __syncthreads();   // LDS build complete; read-only from here on

    half8 p0 = Bf[0 * 64 + lane], p1 = Bf[1 * 64 + lane];

    #pragma unroll 2
    for (int t = 0; t < TPW; t += 2) {
        // prefetch next tile pair (tail lands in the 2 pad tiles)
        const half8 n0 = Bf[(t + 2) * 64 + lane];
        const half8 n1 = Bf[(t + 3) * 64 + lane];

        // ---- phase A: a0-rows vs both B tiles ----
        {
            f32x16 acc0, acc1;
            MFMA_V(acc0, a0, p0, zero16);
            MFMA_V(acc1, a0, p1, zero16);
            __builtin_amdgcn_sched_barrier(0);
            asm volatile("s_nop 7\n\ts_nop 7\n\ts_nop 3");   // 20cyc hazard gap
            __builtin_amdgcn_sched_barrier(0);
            #pragma unroll
            for (int r = 0; r < 16; ++r) MIN3(rm0[r], acc0[r], acc1[r]);
        }
        // ---- phase B: a1-rows vs both B tiles ----
        {
            f32x16 acc0, acc1;
            MFMA_V(acc0, a1, p0, zero16);
            MFMA_V(acc1, a1, p1, zero16);
            __builtin_amdgcn_sched_barrier(0);
            asm volatile("s_nop 7\n\ts_nop 7\n\ts_nop 3");
            __builtin_amdgcn_sched_barrier(0);
            #pragma unroll
            for (int r = 0; r < 16; ++r) MIN3(rm1[r], acc0[r], acc1[r]);
        }

        p0 = n0; p1 = n1;
    }

    // ---- cross-column min (32 cols) + store; row map (r&3)+8*(r>>2)+4*g ----
    const size_t obase = (((size_t)dir * NB + b) * SPLITS + qs) * NPTS + pbase;
    #pragma unroll
    for (int r = 0; r < 16; ++r) {
        float v = rm0[r];
        v = fminf(v, __shfl_xor(v, 1, 64));
        v = fminf(v, __shfl_xor(v, 2, 64));
        v = fminf(v, __shfl_xor(v, 4, 64));
        v = fminf(v, __shfl_xor(v, 8, 64));
        v = fminf(v, __shfl_xor(v, 16, 64));
        float u = rm1[r];
        u = fminf(u, __shfl_xor(u, 1, 64));
        u = fminf(u, __shfl_xor(u, 2, 64));
        u = fminf(u, __shfl_xor(u, 8, 64));
        u = fminf(u, __shfl_xor(u, 4, 64));
        u = fminf(u, __shfl_xor(u, 16, 64));
        if (col == 0) {
            const int row = (r & 3) + 8 * (r >> 2) + 4 * g;
            ws_row[obase + row]      = v;
            ws_row[obase + 32 + row] = u;
        }
    }
}

// ---------- reduce: 256 blocks; min over 8 splits, block partial sums ----------
__global__ __launch_bounds__(256) void chamfer_reduce(
    const float* __restrict__ ws_row, float* __restrict__ partial)
{
    int bid = blockIdx.x;                    // 2 dir x 4 b x 32 slices
    const int sl  = bid & 31; bid >>= 5;
    const int b   = bid & 3;  bid >>= 2;
    const int dir = bid;

    const int p = sl * 256 + threadIdx.x;
    const float* base = ws_row + (((size_t)dir * NB + b) * SPLITS) * NPTS + p;
    float m0 = fminf(base[0],            base[NPTS]);
    float m1 = fminf(base[2 * NPTS],     base[3 * NPTS]);
    float m2 = fminf(base[4 * NPTS],     base[5 * NPTS]);
    float m3 = fminf(base[6 * NPTS],     base[7 * NPTS]);
    float sum = fminf(fminf(m0, m1), fminf(m2, m3));

    for (int off = 32; off; off >>= 1) sum += __shfl_down(sum, off, 64);
    __shared__ float red[4];
    if (!(threadIdx.x & 63)) red[threadIdx.x >> 6] = sum;
    __syncthreads();
    if (!threadIdx.x)
        partial[blockIdx.x] = red[0] + red[1] + red[2] + red[3];
}

// ---------- final: 4 blocks x 64 thr; each b sums its 64 partials ----------
__global__ __launch_bounds__(64) void chamfer_final(
    const float* __restrict__ partial, float* __restrict__ out)
{
    const int b = blockIdx.x, t = threadIdx.x;
    const int dir = t >> 5, sl = t & 31;
    float v = partial[(((size_t)dir * NB + b) << 5) + sl];
    for (int off = 32; off; off >>= 1) v += __shfl_down(v, off, 64);
    if (!t) out[b] = v * (1.0f / (float)NPTS);
}

extern "C" void kernel_launch(void* const* d_in, const int* in_sizes, int n_in,
                              void* d_out, int out_size, void* d_ws, size_t ws_size,
                              hipStream_t stream)
{
    const float* pc1 = (const float*)d_in[0];
    const float* pc2 = (const float*)d_in[1];
    float* out = (float*)d_out;

    char* ws = (char*)d_ws;
    float* ws_row  = (float*)ws;                // 2*4*8*8192*4B = 2 MiB
    float* partial = (float*)(ws + (2 << 20));  // 1 KiB

    chamfer_main<<<2048, 256, 0, stream>>>(pc1, pc2, ws_row);
    chamfer_reduce<<<256, 256, 0, stream>>>(ws_row, partial);
    chamfer_final<<<NB, 64, 0, stream>>>(partial, out);
}